// Round 7
// baseline (213.550 us; speedup 1.0000x reference)
//
#include <hip/hip_runtime.h>

// ODE-RNN encoder: B=2048, T=64, HID=16, adaptive Tsit5 + GRU.
// Round 12: DUAL-STREAM software interleave. R4-R6 established: single-chain
// latency-bound at ~55% issue utilization (1 wave/SIMD); chain micro-trims
// exhausted (R6 neutral); a 2nd wave/SIMD regresses (R1, front-end contention).
// So: two INDEPENDENT samples' ODE chains interleaved in ONE wave's
// instruction stream -> each chain's DPP/transcendental stalls are filled by
// the other's ready ops, no cross-wave contention. 2 lane-parallel x 2
// streams = 4 samples/wave, 512 blocks x 64. Weights shared across streams.
// Early exit = __all over 4 samples (R1: step counts ~uniform, max-of-4 ok);
// finished streams run bitwise no-op iterations (d=0 path, ref semantics).
// R6's gathered-stage-2 reverted: issue-bound now, instr count > chain depth.
// Kept folds: tanh affine (w2'=-2*TS*w2, w3'=-2*w3, seed+=rowsum), activation
// scales in weights, dinv=d*rcp(scale4) parallel to k7, 0.9 in exp2, med3.
// Structure per stream (R9): skewed state, col-split dot (3-DPP gather,
// 4 pk-FMAs rows j/j+8, ROR8 B-ship, permlane32_swap pair-sum, ROR4_HI).

#define T_STEPS 64
#define NB 2048
#define N_ODE_STEPS 16

typedef float v2f __attribute__((ext_vector_type(2)));
typedef int v2i __attribute__((ext_vector_type(2)));

__device__ __forceinline__ v2f make2(float a, float b) { v2f r; r.x = a; r.y = b; return r; }

// row_ror:r  => dst lane n gets src lane (n - r) & 15 (within 16-lane row)
#define ROR(x, r) __int_as_float(__builtin_amdgcn_update_dpp( \
    0, __float_as_int(x), 0x120 + (r), 0xF, 0xF, true))

// rotate-by-4 applied ONLY to rows 2,3 (lanes 32-63); rows 0,1 keep x.
#define ROR4_HI(x) __int_as_float(__builtin_amdgcn_update_dpp( \
    __float_as_int(x), __float_as_int(x), 0x124, 0xC, 0xF, false))

__device__ __forceinline__ float rsum16(float v) {
  v += ROR(v, 8);
  v += ROR(v, 4);
  v += ROR(v, 2);
  v += ROR(v, 1);
  return v;  // all 16 lanes hold the row sum (bitwise lane-uniform)
}

// cross-half combine: returns part + part_from(lane^32); bitwise symmetric.
__device__ __forceinline__ float xhalf_sum(float part) {
  v2i pr = __builtin_amdgcn_permlane32_swap(
      __float_as_int(part), __float_as_int(part), false, false);
  return __int_as_float(pr[0]) + __int_as_float(pr[1]);
}

struct G2 { v2f a, b; };

// rotations 0..3 of the (skewed) state within each 16-row: 3 DPP, depth 2
__device__ __forceinline__ G2 gather4(float x) {
  float r1 = ROR(x, 1);
  float r2 = ROR(x, 2);
  float r3 = ROR(r2, 1);
  G2 g; g.a = make2(x, r1); g.b = make2(r2, r3); return g;
}

// Full 16-col dot for row j (at every lane), then re-skewed to state layout.
__device__ __forceinline__ float dotG(const v2f (&WA)[2], const v2f (&WB)[2],
                                      const G2& g, float seed) {
  v2f aa = __builtin_elementwise_fma(g.a, WA[0], make2(seed, 0.0f));
  v2f bb = g.a * WB[0];
  aa = __builtin_elementwise_fma(g.b, WA[1], aa);
  bb = __builtin_elementwise_fma(g.b, WB[1], bb);
  float a  = aa.x + aa.y;          // A partial: row j, this lane's 4 cols
  float bs = bb.x + bb.y;          // B partial: row j+8, this lane's 4 cols
  float part = a + ROR(bs, 8);     // row j partial: 8 cols (this half)
  return ROR4_HI(xhalf_sum(part)); // all 16 cols, re-skewed
}

// tanh residual: r = rcp(exp2(p)+1); tanh = 1-2r folded into consumer weights.
__device__ __forceinline__ float tanh_res(float p) {
  return __builtin_amdgcn_rcpf(__builtin_amdgcn_exp2f(p) + 1.0f);
}

// sigmoid from a PRE-SCALED argument p = -log2(e)*x
__device__ __forceinline__ float sig_p(float p) {
  float e = __builtin_amdgcn_exp2f(p);
  return __builtin_amdgcn_rcpf(1.0f + e);
}

// unscaled tanh (n-gate: input is a runtime product; output used nonlinearly)
__device__ __forceinline__ float fast_tanh(float x) {
  float e = __builtin_amdgcn_exp2f(x * 2.885390081777927f);  // 2*log2(e)
  return fmaf(-2.0f, __builtin_amdgcn_rcpf(e + 1.0f), 1.0f);
}

// DUAL MLP: two independent chains share one instruction stream; the
// scheduler interleaves them so each chain's stalls cover the other's.
__device__ __forceinline__ void mlp2(float uA, float uB,
    const v2f (&w1a)[2], const v2f (&w1b)[2], float b1s,
    const v2f (&w2a)[2], const v2f (&w2b)[2], float b2s,
    const v2f (&w3a)[2], const v2f (&w3b)[2], float b3s,
    float& kA, float& kB) {
  G2 gA = gather4(uA);
  G2 gB = gather4(uB);
  float r1A = tanh_res(dotG(w1a, w1b, gA, b1s));
  float r1B = tanh_res(dotG(w1a, w1b, gB, b1s));
  G2 hA = gather4(r1A);
  G2 hB = gather4(r1B);
  float r2A = tanh_res(dotG(w2a, w2b, hA, b2s));
  float r2B = tanh_res(dotG(w2a, w2b, hB, b2s));
  G2 qA = gather4(r2A);
  G2 qB = gather4(r2B);
  kA = dotG(w3a, w3b, qA, b3s);
  kB = dotG(w3a, w3b, qB, b3s);
}

__global__
__attribute__((amdgpu_flat_work_group_size(64, 64), amdgpu_waves_per_eu(1, 1)))
void odern_kernel(
    const float* __restrict__ x_seq,
    const float* __restrict__ w1, const float* __restrict__ b1,
    const float* __restrict__ w2, const float* __restrict__ b2,
    const float* __restrict__ w3, const float* __restrict__ b3,
    const float* __restrict__ gru_wih, const float* __restrict__ gru_whh,
    const float* __restrict__ gru_b, const float* __restrict__ gru_bn,
    const float* __restrict__ pred_w, const float* __restrict__ pred_b,
    float* __restrict__ out) {
  const int tid = threadIdx.x;
  const int j = tid & 15;          // lane position within 16-row
  const int row16 = tid >> 4;      // 0..3
  const int smp = row16 & 1;       // lane-parallel sample: rows {0,2}=0, {1,3}=1
  const int hf = row16 >> 1;       // half: 0 = cols j..j-7, 1 = cols j-4..j-15
  const int bA = blockIdx.x * 4 + smp;   // stream A sample
  const int bB = bA + 2;                 // stream B sample
  const int jj = (j + 8) & 15;     // B-dot row
  const int base = (j - 4 * hf) & 15;  // hidden index of this lane's state slot

  const float TS = 2.885390081777927f;    // 2*log2(e)
  const float SS = -1.4426950408889634f;  // -log2(e)
  const float N2TS = -5.770780163555854f; // -2*TS

  // rowsums for the tanh affine fold (seeds, hf=0/row-j only)
  float rs2 = 0.0f, rs3 = 0.0f;
#pragma unroll
  for (int c = 0; c < 16; ++c) { rs2 += w2[j * 16 + c]; rs3 += w3[j * 16 + c]; }

  v2f w1a[2], w1b[2], w2a[2], w2b[2], w3a[2], w3b[2];
  v2f wha[2], whb[2], wza[2], wzb[2], wna[2], wnb[2];
#pragma unroll
  for (int p = 0; p < 2; ++p) {
    const int ca = (base - 2 * p) & 15;
    const int cb = (base - 2 * p - 1) & 15;
    w1a[p] = make2(w1[j * 16 + ca] * TS,  w1[j * 16 + cb] * TS);
    w1b[p] = make2(w1[jj * 16 + ca] * TS, w1[jj * 16 + cb] * TS);
    w2a[p] = make2(w2[j * 16 + ca] * N2TS,  w2[j * 16 + cb] * N2TS);
    w2b[p] = make2(w2[jj * 16 + ca] * N2TS, w2[jj * 16 + cb] * N2TS);
    w3a[p] = make2(w3[j * 16 + ca] * -2.0f,  w3[j * 16 + cb] * -2.0f);
    w3b[p] = make2(w3[jj * 16 + ca] * -2.0f, w3[jj * 16 + cb] * -2.0f);
    wha[p] = make2(gru_whh[j * 16 + ca] * SS,         gru_whh[j * 16 + cb] * SS);
    whb[p] = make2(gru_whh[jj * 16 + ca] * SS,        gru_whh[jj * 16 + cb] * SS);
    wza[p] = make2(gru_whh[(16 + j) * 16 + ca] * SS,  gru_whh[(16 + j) * 16 + cb] * SS);
    wzb[p] = make2(gru_whh[(16 + jj) * 16 + ca] * SS, gru_whh[(16 + jj) * 16 + cb] * SS);
    wna[p] = make2(gru_whh[(32 + j) * 16 + ca],  gru_whh[(32 + j) * 16 + cb]);
    wnb[p] = make2(gru_whh[(32 + jj) * 16 + ca], gru_whh[(32 + jj) * 16 + cb]);
  }
  // Seeds injected once per output row via the hf=0 A-chain.
  const float b1s = hf ? 0.0f : b1[j] * TS;
  const float b2s = hf ? 0.0f : (b2[j] + rs2) * TS;   // + rowsum(w2): h1=1-2r fold
  const float b3s = hf ? 0.0f : b3[j] + rs3;          // + rowsum(w3): h2=1-2r fold
  const float wih_r0 = hf ? 0.0f : gru_wih[j * 2] * SS;
  const float wih_r1 = hf ? 0.0f : gru_wih[j * 2 + 1] * SS;
  const float wih_z0 = hf ? 0.0f : gru_wih[(16 + j) * 2] * SS;
  const float wih_z1 = hf ? 0.0f : gru_wih[(16 + j) * 2 + 1] * SS;
  const float gb_r = hf ? 0.0f : gru_b[j] * SS;
  const float gb_z = hf ? 0.0f : gru_b[16 + j] * SS;
  const float bns  = hf ? 0.0f : gru_bn[j];
  const float wih_n0 = gru_wih[(32 + base) * 2];
  const float wih_n1 = gru_wih[(32 + base) * 2 + 1];
  const float gb_n = gru_b[32 + base];
  const float pwv = pred_w[base], pbv = pred_b[0];

  const float* xpA = x_seq + (size_t)bA * (T_STEPS * 2);
  const float* xpB = x_seq + (size_t)bB * (T_STEPS * 2);

  float hstA = 0.0f, hstB = 0.0f;
#pragma unroll 1
  for (int t = 0; t < T_STEPS; ++t) {
    const float x0A = xpA[2 * t], x1A = xpA[2 * t + 1];
    const float x0B = xpB[2 * t], x1B = xpB[2 * t + 1];

    // ---- adaptive Tsit5, two independent solves interleaved ----
    float yA = hstA, yB = hstB;
    float ttA = 0.0f, dtA = 1.0f, ttB = 0.0f, dtB = 1.0f;
    float k1A, k1B;
    mlp2(yA, yB, w1a, w1b, b1s, w2a, w2b, b2s, w3a, w3b, b3s, k1A, k1B);
#pragma unroll 1
    for (int s = 0; s < N_ODE_STEPS; ++s) {
      // Exit when all 4 samples (2 lanes x 2 streams) are done. A finished
      // stream runs bitwise no-op iterations (d=0), matching the reference.
      if (__all((ttA >= 1.0f) && (ttB >= 1.0f))) break;

      const float dA = fminf(dtA, 1.0f - ttA);
      const float dB = fminf(dtB, 1.0f - ttB);

      float k2A, k2B;
      mlp2(fmaf(dA, 0.161f * k1A, yA), fmaf(dB, 0.161f * k1B, yB),
           w1a, w1b, b1s, w2a, w2b, b2s, w3a, w3b, b3s, k2A, k2B);

      float s3A = fmaf(0.335480655492357f, k2A, -0.008480655492356989f * k1A);
      float s3B = fmaf(0.335480655492357f, k2B, -0.008480655492356989f * k1B);
      float k3A, k3B;
      mlp2(fmaf(dA, s3A, yA), fmaf(dB, s3B, yB),
           w1a, w1b, b1s, w2a, w2b, b2s, w3a, w3b, b3s, k3A, k3B);

      float s4A = fmaf(4.3622954328695815f, k3A,
                  fmaf(-6.359448489975075f, k2A, 2.8971530571054935f * k1A));
      float s4B = fmaf(4.3622954328695815f, k3B,
                  fmaf(-6.359448489975075f, k2B, 2.8971530571054935f * k1B));
      float k4A, k4B;
      mlp2(fmaf(dA, s4A, yA), fmaf(dB, s4B, yB),
           w1a, w1b, b1s, w2a, w2b, b2s, w3a, w3b, b3s, k4A, k4B);

      float s5A = fmaf(-0.09249506636175525f, k4A,
                  fmaf(7.4955393428898365f, k3A,
                  fmaf(-11.748883564062828f, k2A, 5.325864828439257f * k1A)));
      float s5B = fmaf(-0.09249506636175525f, k4B,
                  fmaf(7.4955393428898365f, k3B,
                  fmaf(-11.748883564062828f, k2B, 5.325864828439257f * k1B)));
      float k5A, k5B;
      mlp2(fmaf(dA, s5A, yA), fmaf(dB, s5B, yB),
           w1a, w1b, b1s, w2a, w2b, b2s, w3a, w3b, b3s, k5A, k5B);

      float s6A = fmaf(-0.028269050394068383f, k5A,
                  fmaf(-0.071584973281401f, k4A,
                  fmaf(8.159367898576159f, k3A,
                  fmaf(-12.92096931784711f, k2A, 5.86145544294642f * k1A))));
      float s6B = fmaf(-0.028269050394068383f, k5B,
                  fmaf(-0.071584973281401f, k4B,
                  fmaf(8.159367898576159f, k3B,
                  fmaf(-12.92096931784711f, k2B, 5.86145544294642f * k1B))));
      float k6A, k6B;
      mlp2(fmaf(dA, s6A, yA), fmaf(dB, s6B, yB),
           w1a, w1b, b1s, w2a, w2b, b2s, w3a, w3b, b3s, k6A, k6B);

      float syA = fmaf(2.324710524099774f, k6A,
                  fmaf(-3.290069515436081f, k5A,
                  fmaf(1.379008574103742f, k4A,
                  fmaf(0.4798896504144996f, k3A,
                  fmaf(0.01f, k2A, 0.09646076681806523f * k1A)))));
      float syB = fmaf(2.324710524099774f, k6B,
                  fmaf(-3.290069515436081f, k5B,
                  fmaf(1.379008574103742f, k4B,
                  fmaf(0.4798896504144996f, k3B,
                  fmaf(0.01f, k2B, 0.09646076681806523f * k1B)))));
      float ynA = fmaf(dA, syA, yA);
      float ynB = fmaf(dB, syB, yB);

      // error scale: ready in parallel with k7's MLPs (needs only y, y_new)
      float sc4A = fmaf(0.04f, fmaxf(fabsf(yA), fabsf(ynA)), 0.0004f);
      float sc4B = fmaf(0.04f, fmaxf(fabsf(yB), fabsf(ynB)), 0.0004f);
      float dinvA = dA * __builtin_amdgcn_rcpf(sc4A);
      float dinvB = dB * __builtin_amdgcn_rcpf(sc4B);

      float k7A, k7B;
      mlp2(ynA, ynB, w1a, w1b, b1s, w2a, w2b, b2s, w3a, w3b, b3s, k7A, k7B);

      float seA = fmaf(0.015151515151515152f, k7A,
                  fmaf(-0.45808210592918697f, k6A,
                  fmaf(0.5823571654525552f, k5A,
                  fmaf(-0.1447110071732629f, k4A,
                  fmaf(0.007880878010261995f, k3A,
                  fmaf(-0.0008164344596567469f, k2A, -0.001780011052225777f * k1A))))));
      float seB = fmaf(0.015151515151515152f, k7B,
                  fmaf(-0.45808210592918697f, k6B,
                  fmaf(0.5823571654525552f, k5B,
                  fmaf(-0.1447110071732629f, k4B,
                  fmaf(0.007880878010261995f, k3B,
                  fmaf(-0.0008164344596567469f, k2B, -0.001780011052225777f * k1B))))));

      float rA = seA * dinvA;
      float rB = seB * dinvB;
      float e2A = rsum16(rA * rA);   // symmetric butterfly: lane-uniform
      float e2B = rsum16(rB * rB);

      const bool accA = e2A <= 1.0f;
      const bool accB = e2B <= 1.0f;
      yA = accA ? ynA : yA;  ttA = accA ? ttA + dA : ttA;  k1A = accA ? k7A : k1A;
      yB = accB ? ynB : yB;  ttB = accB ? ttB + dB : ttB;  k1B = accB ? k7B : k1B;

      float facA = __builtin_amdgcn_exp2f(
          fmaf(-0.1f, __builtin_amdgcn_logf(e2A), -0.15200309344504997f));
      float facB = __builtin_amdgcn_exp2f(
          fmaf(-0.1f, __builtin_amdgcn_logf(e2B), -0.15200309344504997f));
      dtA = dA * __builtin_amdgcn_fmed3f(facA, 0.2f, 10.0f);
      dtB = dB * __builtin_amdgcn_fmed3f(facB, 0.2f, 10.0f);
    }

    // ---- GRU update, both streams (shared weights, one gather each) ----
    float irA = fmaf(wih_r1, x1A, fmaf(wih_r0, x0A, gb_r));
    float izA = fmaf(wih_z1, x1A, fmaf(wih_z0, x0A, gb_z));
    float inA = fmaf(wih_n1, x1A, fmaf(wih_n0, x0A, gb_n));
    float irB = fmaf(wih_r1, x1B, fmaf(wih_r0, x0B, gb_r));
    float izB = fmaf(wih_z1, x1B, fmaf(wih_z0, x0B, gb_z));
    float inB = fmaf(wih_n1, x1B, fmaf(wih_n0, x0B, gb_n));
    G2 gyA = gather4(yA);
    G2 gyB = gather4(yB);
    float prA = dotG(wha, whb, gyA, irA);
    float prB = dotG(wha, whb, gyB, irB);
    float pzA = dotG(wza, wzb, gyA, izA);
    float pzB = dotG(wza, wzb, gyB, izB);
    float hnA = dotG(wna, wnb, gyA, bns);
    float hnB = dotG(wna, wnb, gyB, bns);
    float rgA = sig_p(prA), rgB = sig_p(prB);
    float zgA = sig_p(pzA), zgB = sig_p(pzB);
    float ngA = fast_tanh(fmaf(rgA, hnA, inA));
    float ngB = fast_tanh(fmaf(rgB, hnB, inB));
    hstA = fmaf(zgA, yA - ngA, ngA);
    hstB = fmaf(zgB, yB - ngB, ngB);
  }

  // ---- final projection ----
  float psA = rsum16(hstA * pwv);
  float psB = rsum16(hstB * pwv);
  if (hf == 0 && j == 0) {
    out[bA] = psA + pbv;
    out[bB] = psB + pbv;
  }
}

extern "C" void kernel_launch(void* const* d_in, const int* in_sizes, int n_in,
                              void* d_out, int out_size, void* d_ws, size_t ws_size,
                              hipStream_t stream) {
  (void)in_sizes; (void)n_in; (void)out_size; (void)d_ws; (void)ws_size;
  odern_kernel<<<dim3(NB / 4), dim3(64), 0, stream>>>(
      (const float*)d_in[0],
      (const float*)d_in[1], (const float*)d_in[2],
      (const float*)d_in[3], (const float*)d_in[4],
      (const float*)d_in[5], (const float*)d_in[6],
      (const float*)d_in[7], (const float*)d_in[8],
      (const float*)d_in[9], (const float*)d_in[10],
      (const float*)d_in[11], (const float*)d_in[12],
      (float*)d_out);
}

// Round 8
// 179.929 us; speedup vs baseline: 1.1869x; 1.1869x over previous
//
#include <hip/hip_runtime.h>

// ODE-RNN encoder: B=2048, T=64, HID=16, adaptive Tsit5 + GRU.
// Round 13: CROSS-LANE CHAIN SHORTENING. R7 proved dual-stream interleave
// hides the chain at ~100% issue eff but B=2048 is too small for any
// stream/lane config to beat the chain-bound optimum (all land >=0.88x vs
// 0.80 normalized). R5/R6 proved glue deletions don't move L -> L is DPP-hop
// dominated. This round removes serial cross-lane hops from all 18 dots:
//  (E) depth-1 gather: row_ror:N is legal for any N in 1..15 -> all rotations
//      direct from x (was a depth-2 tree). -1 serial DPP per gather.
//  (D) no ROR8 B-ship: lane j's second partial is ROW j cols base-8..-11
//      (gathered by direct rot 8..11, parallel) instead of row j+8 over the
//      same cols (which needed a serial ROR8+add before the combine).
//      Reduce: 4 parallel pk-mul/fma -> add tree -> permlane -> add -> ROR4_HI.
//  Coverage: hf=0 row j gets cols {j..j-3}u{j-8..j-11}, hf=1 {j-4..j-7}u
//  {j-12..j-15}; union over halves (permlane32_swap pair-sum) = all 16. OK.
// Kept: R5/R6 folds (tanh affine into consumer weights, activation scales in
// weights, dinv parallel to k7, 0.9 in exp2, med3 clamp). R6's gathered-
// stage-2 reverted (neutral). Structure: 32 lanes/sample, 2 samples/wave,
// 1024 blocks x 64, skewed state, symmetric-butterfly rsum16 (lane-uniform).

#define T_STEPS 64
#define NB 2048
#define N_ODE_STEPS 16

typedef float v2f __attribute__((ext_vector_type(2)));
typedef int v2i __attribute__((ext_vector_type(2)));

__device__ __forceinline__ v2f make2(float a, float b) { v2f r; r.x = a; r.y = b; return r; }

// row_ror:r  => dst lane n gets src lane (n - r) & 15 (within 16-lane row)
#define ROR(x, r) __int_as_float(__builtin_amdgcn_update_dpp( \
    0, __float_as_int(x), 0x120 + (r), 0xF, 0xF, true))

// rotate-by-4 applied ONLY to rows 2,3 (lanes 32-63); rows 0,1 keep x.
#define ROR4_HI(x) __int_as_float(__builtin_amdgcn_update_dpp( \
    __float_as_int(x), __float_as_int(x), 0x124, 0xC, 0xF, false))

__device__ __forceinline__ float rsum16(float v) {
  v += ROR(v, 8);
  v += ROR(v, 4);
  v += ROR(v, 2);
  v += ROR(v, 1);
  return v;  // all 16 lanes hold the row sum (bitwise lane-uniform)
}

// cross-half combine: returns part + part_from(lane^32); bitwise symmetric.
__device__ __forceinline__ float xhalf_sum(float part) {
  v2i pr = __builtin_amdgcn_permlane32_swap(
      __float_as_int(part), __float_as_int(part), false, false);
  return __int_as_float(pr[0]) + __int_as_float(pr[1]);
}

struct G4 { v2f a, b, c, d; };

// rotations {0,1,2,3, 8,9,10,11} of the skewed state: 7 DPP, ALL depth 1.
__device__ __forceinline__ G4 gatherD(float x) {
  G4 g;
  g.a = make2(x,          ROR(x, 1));
  g.b = make2(ROR(x, 2),  ROR(x, 3));
  g.c = make2(ROR(x, 8),  ROR(x, 9));
  g.d = make2(ROR(x, 10), ROR(x, 11));
  return g;
}

// Full 16-col dot for row j at every lane, re-skewed to state layout.
// WA = row j cols base-{0..3}; WB = row j cols base-8-{0..3}.
// 4 parallel pk ops -> add tree -> extract -> permlane pair-sum -> re-skew.
__device__ __forceinline__ float dotG(const v2f (&WA)[2], const v2f (&WB)[2],
                                      const G4& g, float seed) {
  v2f t0 = __builtin_elementwise_fma(g.a, WA[0], make2(seed, 0.0f));
  v2f t1 = g.b * WA[1];
  v2f t2 = g.c * WB[0];
  v2f t3 = g.d * WB[1];
  v2f s = (t0 + t2) + (t1 + t3);
  float part = s.x + s.y;          // this row's 8 cols (this half's blocks)
  return ROR4_HI(xhalf_sum(part)); // + other half's 8 cols, re-skewed
}

// tanh residual: r = rcp(exp2(p)+1); tanh = 1-2r folded into consumer weights.
__device__ __forceinline__ float tanh_res(float p) {
  return __builtin_amdgcn_rcpf(__builtin_amdgcn_exp2f(p) + 1.0f);
}

// sigmoid from a PRE-SCALED argument p = -log2(e)*x
__device__ __forceinline__ float sig_p(float p) {
  float e = __builtin_amdgcn_exp2f(p);
  return __builtin_amdgcn_rcpf(1.0f + e);
}

// unscaled tanh (n-gate: input is a runtime product; output used nonlinearly)
__device__ __forceinline__ float fast_tanh(float x) {
  float e = __builtin_amdgcn_exp2f(x * 2.885390081777927f);  // 2*log2(e)
  return fmaf(-2.0f, __builtin_amdgcn_rcpf(e + 1.0f), 1.0f);
}

__device__ __forceinline__ float mlp_f(float u,
    const v2f (&w1a)[2], const v2f (&w1b)[2], float b1s,
    const v2f (&w2a)[2], const v2f (&w2b)[2], float b2s,
    const v2f (&w3a)[2], const v2f (&w3b)[2], float b3s) {
  G4 g = gatherD(u);
  float r1v = tanh_res(dotG(w1a, w1b, g, b1s));      // w1,b1 scaled by TS
  G4 h = gatherD(r1v);
  float r2v = tanh_res(dotG(w2a, w2b, h, b2s));      // w2' = -2*TS*w2
  G4 q = gatherD(r2v);
  return dotG(w3a, w3b, q, b3s);                     // w3' = -2*w3 -> true k
}

__global__
__attribute__((amdgpu_flat_work_group_size(64, 64), amdgpu_waves_per_eu(1, 1)))
void odern_kernel(
    const float* __restrict__ x_seq,
    const float* __restrict__ w1, const float* __restrict__ b1,
    const float* __restrict__ w2, const float* __restrict__ b2,
    const float* __restrict__ w3, const float* __restrict__ b3,
    const float* __restrict__ gru_wih, const float* __restrict__ gru_whh,
    const float* __restrict__ gru_b, const float* __restrict__ gru_bn,
    const float* __restrict__ pred_w, const float* __restrict__ pred_b,
    float* __restrict__ out) {
  const int tid = threadIdx.x;
  const int j = tid & 15;          // lane position within 16-row
  const int row16 = tid >> 4;      // 0..3
  const int smp = row16 & 1;       // sample-in-wave: rows {0,2}=0, {1,3}=1
  const int hf = row16 >> 1;       // half: 0 = col-blocks {0,8}, 1 = {4,12}
  const int b = blockIdx.x * 2 + smp;
  const int base = (j - 4 * hf) & 15;  // hidden index of this lane's state slot

  const float TS = 2.885390081777927f;    // 2*log2(e)
  const float SS = -1.4426950408889634f;  // -log2(e)
  const float N2TS = -5.770780163555854f; // -2*TS

  // rowsums for the tanh affine fold (seeds, hf=0/row-j only)
  float rs2 = 0.0f, rs3 = 0.0f;
#pragma unroll
  for (int c = 0; c < 16; ++c) { rs2 += w2[j * 16 + c]; rs3 += w3[j * 16 + c]; }

  // WA[p] = (M[j][ca], M[j][cb]), c = (base-2p)&15 / (base-2p-1)&15
  // WB[p] = same row j, cols (c-8)&15 = c^8  (second col-block)
  v2f w1a[2], w1b[2], w2a[2], w2b[2], w3a[2], w3b[2];
  v2f wha[2], whb[2], wza[2], wzb[2], wna[2], wnb[2];
#pragma unroll
  for (int p = 0; p < 2; ++p) {
    const int ca = (base - 2 * p) & 15;
    const int cb = (base - 2 * p - 1) & 15;
    const int ca8 = ca ^ 8;
    const int cb8 = cb ^ 8;
    w1a[p] = make2(w1[j * 16 + ca] * TS,   w1[j * 16 + cb] * TS);
    w1b[p] = make2(w1[j * 16 + ca8] * TS,  w1[j * 16 + cb8] * TS);
    w2a[p] = make2(w2[j * 16 + ca] * N2TS,  w2[j * 16 + cb] * N2TS);
    w2b[p] = make2(w2[j * 16 + ca8] * N2TS, w2[j * 16 + cb8] * N2TS);
    w3a[p] = make2(w3[j * 16 + ca] * -2.0f,  w3[j * 16 + cb] * -2.0f);
    w3b[p] = make2(w3[j * 16 + ca8] * -2.0f, w3[j * 16 + cb8] * -2.0f);
    wha[p] = make2(gru_whh[j * 16 + ca] * SS,  gru_whh[j * 16 + cb] * SS);
    whb[p] = make2(gru_whh[j * 16 + ca8] * SS, gru_whh[j * 16 + cb8] * SS);
    wza[p] = make2(gru_whh[(16 + j) * 16 + ca] * SS,  gru_whh[(16 + j) * 16 + cb] * SS);
    wzb[p] = make2(gru_whh[(16 + j) * 16 + ca8] * SS, gru_whh[(16 + j) * 16 + cb8] * SS);
    wna[p] = make2(gru_whh[(32 + j) * 16 + ca],  gru_whh[(32 + j) * 16 + cb]);
    wnb[p] = make2(gru_whh[(32 + j) * 16 + ca8], gru_whh[(32 + j) * 16 + cb8]);
  }
  // Seeds injected once per output row via the hf=0 A-chain.
  const float b1s = hf ? 0.0f : b1[j] * TS;
  const float b2s = hf ? 0.0f : (b2[j] + rs2) * TS;   // + rowsum(w2): h1=1-2r fold
  const float b3s = hf ? 0.0f : b3[j] + rs3;          // + rowsum(w3): h2=1-2r fold
  const float wih_r0 = hf ? 0.0f : gru_wih[j * 2] * SS;
  const float wih_r1 = hf ? 0.0f : gru_wih[j * 2 + 1] * SS;
  const float wih_z0 = hf ? 0.0f : gru_wih[(16 + j) * 2] * SS;
  const float wih_z1 = hf ? 0.0f : gru_wih[(16 + j) * 2 + 1] * SS;
  const float gb_r = hf ? 0.0f : gru_b[j] * SS;
  const float gb_z = hf ? 0.0f : gru_b[16 + j] * SS;
  const float bns  = hf ? 0.0f : gru_bn[j];
  const float wih_n0 = gru_wih[(32 + base) * 2];
  const float wih_n1 = gru_wih[(32 + base) * 2 + 1];
  const float gb_n = gru_b[32 + base];
  const float pwv = pred_w[base], pbv = pred_b[0];

  const float* xp = x_seq + (size_t)b * (T_STEPS * 2);

  float hst = 0.0f;
#pragma unroll 1
  for (int t = 0; t < T_STEPS; ++t) {
    const float x0 = xp[2 * t];
    const float x1 = xp[2 * t + 1];

    // ---- adaptive Tsit5 from t=0 to t=1, <=16 iterations, early exit ----
    float y = hst;
    float tt = 0.0f, dt = 1.0f;
    float k1 = mlp_f(y, w1a, w1b, b1s, w2a, w2b, b2s, w3a, w3b, b3s);
#pragma unroll 1
    for (int s = 0; s < N_ODE_STEPS; ++s) {
      // Wave-uniform early exit (accept logic is row-uniform per sample).
      if (__all(tt >= 1.0f)) break;

      const float dt_c = fminf(dt, 1.0f - tt);
      const float d = dt_c;

      float k2 = mlp_f(fmaf(d, 0.161f * k1, y),
                       w1a, w1b, b1s, w2a, w2b, b2s, w3a, w3b, b3s);

      float s3 = fmaf(0.335480655492357f, k2, -0.008480655492356989f * k1);
      float k3 = mlp_f(fmaf(d, s3, y), w1a, w1b, b1s, w2a, w2b, b2s, w3a, w3b, b3s);

      float s4 = fmaf(4.3622954328695815f, k3,
                 fmaf(-6.359448489975075f, k2, 2.8971530571054935f * k1));
      float k4 = mlp_f(fmaf(d, s4, y), w1a, w1b, b1s, w2a, w2b, b2s, w3a, w3b, b3s);

      float s5 = fmaf(-0.09249506636175525f, k4,
                 fmaf(7.4955393428898365f, k3,
                 fmaf(-11.748883564062828f, k2, 5.325864828439257f * k1)));
      float k5 = mlp_f(fmaf(d, s5, y), w1a, w1b, b1s, w2a, w2b, b2s, w3a, w3b, b3s);

      float s6 = fmaf(-0.028269050394068383f, k5,
                 fmaf(-0.071584973281401f, k4,
                 fmaf(8.159367898576159f, k3,
                 fmaf(-12.92096931784711f, k2, 5.86145544294642f * k1))));
      float k6 = mlp_f(fmaf(d, s6, y), w1a, w1b, b1s, w2a, w2b, b2s, w3a, w3b, b3s);

      float sy = fmaf(2.324710524099774f, k6,
                 fmaf(-3.290069515436081f, k5,
                 fmaf(1.379008574103742f, k4,
                 fmaf(0.4798896504144996f, k3,
                 fmaf(0.01f, k2, 0.09646076681806523f * k1)))));
      float y_new = fmaf(d, sy, y);

      // error scale: ready in parallel with k7's MLP (only needs y, y_new)
      float scale4 = fmaf(0.04f, fmaxf(fabsf(y), fabsf(y_new)), 0.0004f);
      float dinv = d * __builtin_amdgcn_rcpf(scale4);

      float k7 = mlp_f(y_new, w1a, w1b, b1s, w2a, w2b, b2s, w3a, w3b, b3s);

      float se = fmaf(0.015151515151515152f, k7,
                 fmaf(-0.45808210592918697f, k6,
                 fmaf(0.5823571654525552f, k5,
                 fmaf(-0.1447110071732629f, k4,
                 fmaf(0.007880878010261995f, k3,
                 fmaf(-0.0008164344596567469f, k2, -0.001780011052225777f * k1))))));

      float r = se * dinv;              // err/scale with d folded in
      float err2 = rsum16(r * r);       // symmetric butterfly: lane-uniform

      const bool acc = err2 <= 1.0f;
      y = acc ? y_new : y;
      tt = acc ? tt + dt_c : tt;
      k1 = acc ? k7 : k1;   // FSAL

      // fac = 0.9*err2^-0.1, 0.9 folded: exp2(fma(-0.1, log2(err2), log2 0.9))
      float fac = __builtin_amdgcn_exp2f(
          fmaf(-0.1f, __builtin_amdgcn_logf(err2), -0.15200309344504997f));
      fac = __builtin_amdgcn_fmed3f(fac, 0.2f, 10.0f);
      dt = dt_c * fac;
    }

    // ---- GRU update: one shared gather feeds all 3 dots ----
    float ir  = fmaf(wih_r1, x1, fmaf(wih_r0, x0, gb_r));   // pre-scaled, 0 at hf=1
    float iz  = fmaf(wih_z1, x1, fmaf(wih_z0, x0, gb_z));   // pre-scaled, 0 at hf=1
    float in_ = fmaf(wih_n1, x1, fmaf(wih_n0, x0, gb_n));   // skewed, all lanes
    G4 gy = gatherD(y);
    float pre_r = dotG(wha, whb, gy, ir);    // -log2e*(ir + hr)   (skewed)
    float pre_z = dotG(wza, wzb, gy, iz);    // -log2e*(iz + hz)   (skewed)
    float hnb   = dotG(wna, wnb, gy, bns);   // hn + bn            (skewed)
    float rg = sig_p(pre_r);
    float zg = sig_p(pre_z);
    float ng = fast_tanh(fmaf(rg, hnb, in_));
    hst = fmaf(zg, y - ng, ng);
  }

  // ---- final projection: out[b] = h . pred_w + pred_b ----
  float ps = rsum16(hst * pwv);
  if (hf == 0 && j == 0) out[b] = ps + pbv;   // rows 0,1: one writer per sample
}

extern "C" void kernel_launch(void* const* d_in, const int* in_sizes, int n_in,
                              void* d_out, int out_size, void* d_ws, size_t ws_size,
                              hipStream_t stream) {
  (void)in_sizes; (void)n_in; (void)out_size; (void)d_ws; (void)ws_size;
  odern_kernel<<<dim3(NB / 2), dim3(64), 0, stream>>>(
      (const float*)d_in[0],
      (const float*)d_in[1], (const float*)d_in[2],
      (const float*)d_in[3], (const float*)d_in[4],
      (const float*)d_in[5], (const float*)d_in[6],
      (const float*)d_in[7], (const float*)d_in[8],
      (const float*)d_in[9], (const float*)d_in[10],
      (const float*)d_in[11], (const float*)d_in[12],
      (float*)d_out);
}

// Round 9
// 171.257 us; speedup vs baseline: 1.2470x; 1.0506x over previous
//
#include <hip/hip_runtime.h>

// ODE-RNN encoder: B=2048, T=64, HID=16, adaptive Tsit5 + GRU.
// FINAL (Round 14): revert to the session's empirical best (Round-10 kernel,
// 103.4 us dispatch). Post-R8 model: wall/iter = issue + exposed-latency;
// R5 sits at the valley floor (900 + 740 cy/iter). Measured dead ends:
//  - issue trims (R5 -2.2%, R6 0%): exposed latency floor takes over
//  - chain trims via wider gathers (R8 +7%): added issue lands on the chain
//  - dual-stream ILP (R7 +42%): issue doubles, only 470 cy latency hidden
//  - 2 waves/SIMD (R1 +15%): CU front-end contention
//  - 4 samples/wave configs (R2 1696 cy/iter vs R5 1643)
// B=2048 on 1024 SIMDs forces 2 samples/wave at 1 wave/SIMD; latency-bound
// at VALUBusy ~55% with HBM (<0.1%) and MFMA (0) idle.
// Structure: 32 lanes/sample, 2 samples/wave, 1024 blocks x 64; skewed state
// (hf=0 lane j holds y_j, hf=1 holds y_{j-4}); col-split dot: 3-DPP gather,
// 4 pk-FMAs (rows j & j+8), ROR8 B-ship, permlane32_swap cross-half pair-sum,
// row-masked ROR4 re-skew. Folds: activation scales in weights (TS/SS),
// tanh affine (w2'=-2*TS*w2, w3'=-2*w3, seed+=rowsum) REVERTED to R10 form
// (kept: scale folding, mean-in-scale4, med3 clamp, 0.9-in-exp2, dinv||k7).

#define T_STEPS 64
#define NB 2048
#define N_ODE_STEPS 16

typedef float v2f __attribute__((ext_vector_type(2)));
typedef int v2i __attribute__((ext_vector_type(2)));

__device__ __forceinline__ v2f make2(float a, float b) { v2f r; r.x = a; r.y = b; return r; }

// row_ror:r  => dst lane n gets src lane (n - r) & 15 (within 16-lane row)
#define ROR(x, r) __int_as_float(__builtin_amdgcn_update_dpp( \
    0, __float_as_int(x), 0x120 + (r), 0xF, 0xF, true))

// rotate-by-4 applied ONLY to rows 2,3 (lanes 32-63); rows 0,1 keep x.
#define ROR4_HI(x) __int_as_float(__builtin_amdgcn_update_dpp( \
    __float_as_int(x), __float_as_int(x), 0x124, 0xC, 0xF, false))

__device__ __forceinline__ float rsum16(float v) {
  v += ROR(v, 8);
  v += ROR(v, 4);
  v += ROR(v, 2);
  v += ROR(v, 1);
  return v;  // all 16 lanes hold the row sum (bitwise lane-uniform)
}

// cross-half combine: returns part + part_from(lane^32).
// With both operands equal, v_permlane32_swap returns {own-half, other-half}
// per lane -> their sum is the pair sum at every lane.
__device__ __forceinline__ float xhalf_sum(float part) {
  v2i pr = __builtin_amdgcn_permlane32_swap(
      __float_as_int(part), __float_as_int(part), false, false);
  return __int_as_float(pr[0]) + __int_as_float(pr[1]);
}

struct G2 { v2f a, b; };

// rotations 0..3 of the (skewed) state within each 16-row: 3 DPP, depth 2
__device__ __forceinline__ G2 gather4(float x) {
  float r1 = ROR(x, 1);
  float r2 = ROR(x, 2);
  float r3 = ROR(r2, 1);
  G2 g; g.a = make2(x, r1); g.b = make2(r2, r3); return g;
}

// Full 16-col dot for row j (at every lane), then re-skewed to state layout.
// WA = row j cols {base-0..-3}, WB = row j+8 same cols (base = j-4*hf).
__device__ __forceinline__ float dotG(const v2f (&WA)[2], const v2f (&WB)[2],
                                      const G2& g, float seed) {
  v2f aa = __builtin_elementwise_fma(g.a, WA[0], make2(seed, 0.0f));
  v2f bb = g.a * WB[0];
  aa = __builtin_elementwise_fma(g.b, WA[1], aa);
  bb = __builtin_elementwise_fma(g.b, WB[1], bb);
  float a  = aa.x + aa.y;          // A partial: row j, this lane's 4 cols
  float bs = bb.x + bb.y;          // B partial: row j+8, this lane's 4 cols
  float part = a + ROR(bs, 8);     // row j partial: 8 cols (this half)
  return ROR4_HI(xhalf_sum(part)); // all 16 cols, re-skewed
}

__device__ __forceinline__ float dotAB(const v2f (&WA)[2], const v2f (&WB)[2],
                                       float x, float seed) {
  G2 g = gather4(x);
  return dotG(WA, WB, g, seed);
}

// tanh from a PRE-SCALED argument p = 2*log2(e)*x (scale folded into weights)
__device__ __forceinline__ float tanh_p(float p) {
  float e = __builtin_amdgcn_exp2f(p);
  return fmaf(-2.0f, __builtin_amdgcn_rcpf(e + 1.0f), 1.0f);
}

// sigmoid from a PRE-SCALED argument p = -log2(e)*x
__device__ __forceinline__ float sig_p(float p) {
  float e = __builtin_amdgcn_exp2f(p);
  return __builtin_amdgcn_rcpf(1.0f + e);
}

// unscaled tanh (n-gate: input is a runtime product, can't fold)
__device__ __forceinline__ float fast_tanh(float x) {
  float e = __builtin_amdgcn_exp2f(x * 2.885390081777927f);  // 2*log2(e)
  return fmaf(-2.0f, __builtin_amdgcn_rcpf(e + 1.0f), 1.0f);
}

__device__ __forceinline__ float mlp_f(float u,
    const v2f (&w1a)[2], const v2f (&w1b)[2], float b1s,
    const v2f (&w2a)[2], const v2f (&w2b)[2], float b2s,
    const v2f (&w3a)[2], const v2f (&w3b)[2], float b3s) {
  float h1 = tanh_p(dotAB(w1a, w1b, u, b1s));   // w1/b1 pre-scaled by 2log2e
  float h2 = tanh_p(dotAB(w2a, w2b, h1, b2s));  // w2/b2 pre-scaled by 2log2e
  return dotAB(w3a, w3b, h2, b3s);              // w3/b3 unscaled (k output)
}

__global__
__attribute__((amdgpu_flat_work_group_size(64, 64), amdgpu_waves_per_eu(1, 1)))
void odern_kernel(
    const float* __restrict__ x_seq,
    const float* __restrict__ w1, const float* __restrict__ b1,
    const float* __restrict__ w2, const float* __restrict__ b2,
    const float* __restrict__ w3, const float* __restrict__ b3,
    const float* __restrict__ gru_wih, const float* __restrict__ gru_whh,
    const float* __restrict__ gru_b, const float* __restrict__ gru_bn,
    const float* __restrict__ pred_w, const float* __restrict__ pred_b,
    float* __restrict__ out) {
  const int tid = threadIdx.x;
  const int j = tid & 15;          // lane position within 16-row
  const int row16 = tid >> 4;      // 0..3
  const int smp = row16 & 1;       // sample-in-wave: rows {0,2}=0, {1,3}=1
  const int hf = row16 >> 1;       // half: 0 = cols j..j-7, 1 = cols j-4..j-15
  const int b = blockIdx.x * 2 + smp;
  const int jj = (j + 8) & 15;     // B-dot row
  const int base = (j - 4 * hf) & 15;  // hidden index of this lane's state slot

  const float TS = 2.885390081777927f;    // 2*log2(e)  (tanh input scale)
  const float SS = -1.4426950408889634f;  // -log2(e)   (sigmoid input scale)

  // Per-lane weights: WA[p] = (M[j][c_{2p}], M[j][c_{2p+1}]), c_r = (base-r)&15
  //                   WB[p] = same cols, row jj. w1/w2 & r/z gates pre-scaled.
  v2f w1a[2], w1b[2], w2a[2], w2b[2], w3a[2], w3b[2];
  v2f wha[2], whb[2], wza[2], wzb[2], wna[2], wnb[2];
#pragma unroll
  for (int p = 0; p < 2; ++p) {
    const int ca = (base - 2 * p) & 15;
    const int cb = (base - 2 * p - 1) & 15;
    w1a[p] = make2(w1[j * 16 + ca] * TS,  w1[j * 16 + cb] * TS);
    w1b[p] = make2(w1[jj * 16 + ca] * TS, w1[jj * 16 + cb] * TS);
    w2a[p] = make2(w2[j * 16 + ca] * TS,  w2[j * 16 + cb] * TS);
    w2b[p] = make2(w2[jj * 16 + ca] * TS, w2[jj * 16 + cb] * TS);
    w3a[p] = make2(w3[j * 16 + ca],  w3[j * 16 + cb]);
    w3b[p] = make2(w3[jj * 16 + ca], w3[jj * 16 + cb]);
    wha[p] = make2(gru_whh[j * 16 + ca] * SS,         gru_whh[j * 16 + cb] * SS);
    whb[p] = make2(gru_whh[jj * 16 + ca] * SS,        gru_whh[jj * 16 + cb] * SS);
    wza[p] = make2(gru_whh[(16 + j) * 16 + ca] * SS,  gru_whh[(16 + j) * 16 + cb] * SS);
    wzb[p] = make2(gru_whh[(16 + jj) * 16 + ca] * SS, gru_whh[(16 + jj) * 16 + cb] * SS);
    wna[p] = make2(gru_whh[(32 + j) * 16 + ca],  gru_whh[(32 + j) * 16 + cb]);
    wnb[p] = make2(gru_whh[(32 + jj) * 16 + ca], gru_whh[(32 + jj) * 16 + cb]);
  }
  // Seeds are injected once per output row, via the hf=0 A-chain only.
  const float b1s = hf ? 0.0f : b1[j] * TS;
  const float b2s = hf ? 0.0f : b2[j] * TS;
  const float b3s = hf ? 0.0f : b3[j];
  // r/z gates: only used as dot seeds -> zero at hf=1; pre-scaled by SS.
  const float wih_r0 = hf ? 0.0f : gru_wih[j * 2] * SS;
  const float wih_r1 = hf ? 0.0f : gru_wih[j * 2 + 1] * SS;
  const float wih_z0 = hf ? 0.0f : gru_wih[(16 + j) * 2] * SS;
  const float wih_z1 = hf ? 0.0f : gru_wih[(16 + j) * 2 + 1] * SS;
  const float gb_r = hf ? 0.0f : gru_b[j] * SS;
  const float gb_z = hf ? 0.0f : gru_b[16 + j] * SS;
  const float bns  = hf ? 0.0f : gru_bn[j];
  // n gate input is used ELEMENTWISE (skewed space) -> base-indexed, all lanes.
  const float wih_n0 = gru_wih[(32 + base) * 2];
  const float wih_n1 = gru_wih[(32 + base) * 2 + 1];
  const float gb_n = gru_b[32 + base];
  const float pwv = pred_w[base], pbv = pred_b[0];

  const float* xp = x_seq + (size_t)b * (T_STEPS * 2);

  float hst = 0.0f;
#pragma unroll 1
  for (int t = 0; t < T_STEPS; ++t) {
    const float x0 = xp[2 * t];
    const float x1 = xp[2 * t + 1];

    // ---- adaptive Tsit5 from t=0 to t=1, <=16 iterations, early exit ----
    float y = hst;
    float tt = 0.0f, dt = 1.0f;
    float k1 = mlp_f(y, w1a, w1b, b1s, w2a, w2b, b2s, w3a, w3b, b3s);
#pragma unroll 1
    for (int s = 0; s < N_ODE_STEPS; ++s) {
      // Wave-uniform early exit (accept logic is row-uniform per sample).
      if (__all(tt >= 1.0f)) break;

      const float dt_c = fminf(dt, 1.0f - tt);
      const float d = dt_c;

      float s2 = 0.161f * k1;
      float k2 = mlp_f(fmaf(d, s2, y), w1a, w1b, b1s, w2a, w2b, b2s, w3a, w3b, b3s);

      float s3 = fmaf(0.335480655492357f, k2, -0.008480655492356989f * k1);
      float k3 = mlp_f(fmaf(d, s3, y), w1a, w1b, b1s, w2a, w2b, b2s, w3a, w3b, b3s);

      float s4 = fmaf(4.3622954328695815f, k3,
                 fmaf(-6.359448489975075f, k2, 2.8971530571054935f * k1));
      float k4 = mlp_f(fmaf(d, s4, y), w1a, w1b, b1s, w2a, w2b, b2s, w3a, w3b, b3s);

      float s5 = fmaf(-0.09249506636175525f, k4,
                 fmaf(7.4955393428898365f, k3,
                 fmaf(-11.748883564062828f, k2, 5.325864828439257f * k1)));
      float k5 = mlp_f(fmaf(d, s5, y), w1a, w1b, b1s, w2a, w2b, b2s, w3a, w3b, b3s);

      float s6 = fmaf(-0.028269050394068383f, k5,
                 fmaf(-0.071584973281401f, k4,
                 fmaf(8.159367898576159f, k3,
                 fmaf(-12.92096931784711f, k2, 5.86145544294642f * k1))));
      float k6 = mlp_f(fmaf(d, s6, y), w1a, w1b, b1s, w2a, w2b, b2s, w3a, w3b, b3s);

      float sy = fmaf(2.324710524099774f, k6,
                 fmaf(-3.290069515436081f, k5,
                 fmaf(1.379008574103742f, k4,
                 fmaf(0.4798896504144996f, k3,
                 fmaf(0.01f, k2, 0.09646076681806523f * k1)))));
      float y_new = fmaf(d, sy, y);

      float k7 = mlp_f(y_new, w1a, w1b, b1s, w2a, w2b, b2s, w3a, w3b, b3s);

      float se = fmaf(0.015151515151515152f, k7,
                 fmaf(-0.45808210592918697f, k6,
                 fmaf(0.5823571654525552f, k5,
                 fmaf(-0.1447110071732629f, k4,
                 fmaf(0.007880878010261995f, k3,
                 fmaf(-0.0008164344596567469f, k2, -0.001780011052225777f * k1))))));
      float err = d * se;

      // scale4 = 4*(atol + rtol*max) so that rsum16((err/scale4)^2) directly
      // equals mean((err/scale)^2) (the 1/16 is folded in: (1/4)^2 * 16 = 1).
      float scale4 = fmaf(0.04f, fmaxf(fabsf(y), fabsf(y_new)), 0.0004f);
      float r = err * __builtin_amdgcn_rcpf(scale4);
      float err2 = fmaxf(rsum16(r * r), 1e-16f);

      const bool acc = err2 <= 1.0f;
      y = acc ? y_new : y;
      tt = acc ? tt + dt_c : tt;
      k1 = acc ? k7 : k1;   // FSAL: f(y_new) == k7 bitwise, else keep k1

      float fac = 0.9f * __builtin_amdgcn_exp2f(-0.1f * __builtin_amdgcn_logf(err2));
      fac = __builtin_amdgcn_fmed3f(fac, 0.2f, 10.0f);   // clamp in one op
      dt = dt_c * fac;
    }

    // ---- GRU update: one shared gather feeds all 3 dots ----
    float ir  = fmaf(wih_r1, x1, fmaf(wih_r0, x0, gb_r));   // pre-scaled, 0 at hf=1
    float iz  = fmaf(wih_z1, x1, fmaf(wih_z0, x0, gb_z));   // pre-scaled, 0 at hf=1
    float in_ = fmaf(wih_n1, x1, fmaf(wih_n0, x0, gb_n));   // skewed, all lanes
    G2 gy = gather4(y);
    float pre_r = dotG(wha, whb, gy, ir);    // -log2e*(ir + hr)   (skewed)
    float pre_z = dotG(wza, wzb, gy, iz);    // -log2e*(iz + hz)   (skewed)
    float hnb   = dotG(wna, wnb, gy, bns);   // hn + bn            (skewed)
    float rg = sig_p(pre_r);
    float zg = sig_p(pre_z);
    float ng = fast_tanh(fmaf(rg, hnb, in_));
    hst = fmaf(zg, y - ng, ng);
  }

  // ---- final projection: out[b] = h . pred_w + pred_b ----
  float ps = rsum16(hst * pwv);
  if (hf == 0 && j == 0) out[b] = ps + pbv;   // rows 0,1: one writer per sample
}

extern "C" void kernel_launch(void* const* d_in, const int* in_sizes, int n_in,
                              void* d_out, int out_size, void* d_ws, size_t ws_size,
                              hipStream_t stream) {
  (void)in_sizes; (void)n_in; (void)out_size; (void)d_ws; (void)ws_size;
  odern_kernel<<<dim3(NB / 2), dim3(64), 0, stream>>>(
      (const float*)d_in[0],
      (const float*)d_in[1], (const float*)d_in[2],
      (const float*)d_in[3], (const float*)d_in[4],
      (const float*)d_in[5], (const float*)d_in[6],
      (const float*)d_in[7], (const float*)d_in[8],
      (const float*)d_in[9], (const float*)d_in[10],
      (const float*)d_in[11], (const float*)d_in[12],
      (float*)d_out);
}